// Round 8
// baseline (583.758 us; speedup 1.0000x reference)
//
#include <hip/hip_runtime.h>

// ---------------------------------------------------------------------------
// NASNet controller: 8 sequential LSTM steps (B=4096, H=512) + 16 decisions.
//  - Steps 1-4 run on class representatives (1/8/64/512 rows).
//  - Steps 5-7: full GEMMs on the MFMA pipe via split-bf16 (hi+lo) emulation:
//    C = Ahi@Whi + Ahi@Wlo + Alo@Whi.
//  - R5: XCD superblock blockIdx swizzle (per-XCD set ~fits 4MB L2).
//  - R6: shared-operand products (3 MFMAs per fragment pair).
//  - R7: launch fusions (setup, step0, steps 1/2, ct-space gemm64).
//  - R8: strided-lane decide4 (per-instruction coalescing).
//  - R9 (96KB 3-slice) REVERTED: 1 block/CU lost cross-block overlap (93us).
//  - R10 (all-direct-L2) REVERTED: MFMA waited on per-lane L2 latency (81us).
//  - R11: hybrid. B via glds16->LDS 2-slice prefetch (R4-proven); A direct
//    L2->VGPR double-buffered, loads issued BEFORE the barrier so the
//    barrier's implicit vmcnt(0) drain covers them (compiler cannot sink
//    loads across __syncthreads). Halves LDS traffic, zero exposed A
//    latency, occupancy/cross-block overlap unchanged, bit-identical MFMA
//    order vs R4.
//  - R12: resubmit of R11 verbatim — R7's bench failed on container
//    acquisition (infra flake), not on the kernel (audited: uniform
//    barriers, in-bounds LDS, hazard-free buffers, <=256 VGPR).
// ---------------------------------------------------------------------------

constexpr int Bsz = 4096;
constexpr int Hsz = 512;
constexpr int G4H = 2048;

typedef unsigned short ushort_t;
using short8 = __attribute__((ext_vector_type(8))) short;
using f32x4 = __attribute__((ext_vector_type(4))) float;

__device__ __forceinline__ ushort_t f2bf_hi(float f) {
  unsigned u = __float_as_uint(f);
  u += 0x7FFF + ((u >> 16) & 1);  // RNE
  return (ushort_t)(u >> 16);
}
__device__ __forceinline__ float bf2f(ushort_t h) {
  return __uint_as_float((unsigned)h << 16);
}
__device__ __forceinline__ float sigf(float x) {
  return 1.0f / (1.0f + expf(-x));
}

__device__ __forceinline__ void glds16(const void* gsrc, void* ldst) {
  __builtin_amdgcn_global_load_lds(
      (const __attribute__((address_space(1))) void*)gsrc,
      (__attribute__((address_space(3))) void*)ldst, 16, 0, 0);
}

// ---------------- setup: Eperm (wave-per-col) + Wcat, one launch -----------
__global__ __launch_bounds__(256) void setup_fused(
    const float* __restrict__ emb, const float* __restrict__ w_ih,
    const float* __restrict__ b_ih, const float* __restrict__ b_hh,
    const float* __restrict__ w_hh, float* __restrict__ Eperm,
    ushort_t* __restrict__ Wcat) {
  if (blockIdx.x < 4608) {
    const int lane = threadIdx.x & 63;
    const int wid = (blockIdx.x << 2) + (threadIdx.x >> 6);  // t*2048 + col
    const int t = wid >> 11;
    const int col = wid & 2047;
    const float* er = emb + (size_t)t * Hsz + (lane << 3);
    const float* wr = w_ih + (size_t)col * Hsz + (lane << 3);
    float4 e0 = *(const float4*)(er);
    float4 e1 = *(const float4*)(er + 4);
    float4 w0 = *(const float4*)(wr);
    float4 w1 = *(const float4*)(wr + 4);
    float v = e0.x * w0.x + e0.y * w0.y + e0.z * w0.z + e0.w * w0.w +
              e1.x * w1.x + e1.y * w1.y + e1.z * w1.z + e1.w * w1.w;
#pragma unroll
    for (int off = 32; off > 0; off >>= 1) v += __shfl_xor(v, off, 64);
    if (lane == 0) {
      float val = v + b_ih[col] + b_hh[col];
      Eperm[(size_t)t * G4H + ((col & 511) << 2) + (col >> 9)] = val;
    }
  } else {
    const int b = blockIdx.x - 4608;
    const int ct = b >> 2;
    const int k = ((b & 3) << 8) + threadIdx.x;  // 0..1023
    const int j = ct >> 2, g = ct & 3;
    const float* srcrow = w_hh + (size_t)(g * 512 + j) * Hsz;
    ushort_t out;
    if (k < 512) {
      out = f2bf_hi(srcrow[k]);
    } else {
      float x = srcrow[k - 512];
      ushort_t hi = f2bf_hi(x);
      out = f2bf_hi(x - bf2f(hi));
    }
    Wcat[(size_t)ct * 1536 + k] = out;
  }
}

// ---------------- decide core (wave per row, h as float4 pair) -------------
template <int K>
__device__ __forceinline__ void decide_core(
    const float4 hv0, const float4 hv1, const int lane, const int r,
    const float* __restrict__ wn, const float* __restrict__ bn,
    const float* __restrict__ wopi, const float* __restrict__ bopi,
    const float* __restrict__ gum, float* __restrict__ oan,
    float* __restrict__ oao, float* __restrict__ oln, float* __restrict__ olo,
    float* __restrict__ oen, float* __restrict__ oeo,
    int* __restrict__ act_next, const int* __restrict__ cls_prev,
    int* __restrict__ cls_out) {
  float nl[K];
#pragma unroll
  for (int j = 0; j < K; ++j) {
    const float* w = wn + (size_t)j * Hsz;
    float4 w0 = *(const float4*)(w + (lane << 3));
    float4 w1 = *(const float4*)(w + (lane << 3) + 4);
    float v = hv0.x * w0.x + hv0.y * w0.y + hv0.z * w0.z + hv0.w * w0.w +
              hv1.x * w1.x + hv1.y * w1.y + hv1.z * w1.z + hv1.w * w1.w;
#pragma unroll
    for (int off = 32; off > 0; off >>= 1) v += __shfl_xor(v, off, 64);
    nl[j] = 2.5f * tanhf((v + bn[j]) / 5.0f);
  }
  float ol[8];
#pragma unroll
  for (int j = 0; j < 8; ++j) {
    const float* w = wopi + (size_t)j * Hsz;
    float4 w0 = *(const float4*)(w + (lane << 3));
    float4 w1 = *(const float4*)(w + (lane << 3) + 4);
    float v = hv0.x * w0.x + hv0.y * w0.y + hv0.z * w0.z + hv0.w * w0.w +
              hv1.x * w1.x + hv1.y * w1.y + hv1.z * w1.z + hv1.w * w1.w;
#pragma unroll
    for (int off = 32; off > 0; off >>= 1) v += __shfl_xor(v, off, 64);
    ol[j] = (v + bopi[j]) / 5.0f;
  }

  {
    const float* g = gum + (size_t)r * 8;
    float m = nl[0];
#pragma unroll
    for (int j = 1; j < K; ++j) m = fmaxf(m, nl[j]);
    float se = 0.0f;
#pragma unroll
    for (int j = 0; j < K; ++j) se += expf(nl[j] - m);
    float lse = logf(se);
    int a = 0;
    float best = nl[0] + g[0];
#pragma unroll
    for (int j = 1; j < K; ++j) {
      float v = nl[j] + g[j];
      if (v > best) { best = v; a = j; }
    }
    float ent = 0.0f, sel = 0.0f;
#pragma unroll
    for (int j = 0; j < K; ++j) {
      float lp = nl[j] - m - lse;
      ent -= lp * expf(lp);
      if (j == a) sel = lp;
    }
    if (lane == 0) { oan[r] = (float)a; oln[r] = sel; oen[r] = ent; }
  }
  {
    const float* g = gum + (size_t)Bsz * 8 + (size_t)r * 8;
    float m = ol[0];
#pragma unroll
    for (int j = 1; j < 8; ++j) m = fmaxf(m, ol[j]);
    float se = 0.0f;
#pragma unroll
    for (int j = 0; j < 8; ++j) se += expf(ol[j] - m);
    float lse = logf(se);
    int a = 0;
    float best = ol[0] + g[0];
#pragma unroll
    for (int j = 1; j < 8; ++j) {
      float v = ol[j] + g[j];
      if (v > best) { best = v; a = j; }
    }
    float ent = 0.0f, sel = 0.0f;
#pragma unroll
    for (int j = 0; j < 8; ++j) {
      float lp = ol[j] - m - lse;
      ent -= lp * expf(lp);
      if (j == a) sel = lp;
    }
    if (lane == 0) {
      oao[r] = (float)a; olo[r] = sel; oeo[r] = ent;
      act_next[r] = a;
      if (cls_out) cls_out[r] = (cls_prev ? cls_prev[r] * 8 : 0) + a;
    }
  }
}

// ---------------- decide core, STRIDED h layout: lane holds h[kk*64+lane] --
template <int K>
__device__ __forceinline__ void decide_core_s(
    const float* __restrict__ h8, const int lane, const int r,
    const float* __restrict__ wn, const float* __restrict__ bn,
    const float* __restrict__ wopi, const float* __restrict__ bopi,
    const float* __restrict__ gum, float* __restrict__ oan,
    float* __restrict__ oao, float* __restrict__ oln, float* __restrict__ olo,
    float* __restrict__ oen, float* __restrict__ oeo,
    int* __restrict__ act_next, const int* __restrict__ cls_prev,
    int* __restrict__ cls_out) {
  float nl[K];
#pragma unroll
  for (int j = 0; j < K; ++j) {
    const float* w = wn + (size_t)j * Hsz + lane;
    float v = 0.0f;
#pragma unroll
    for (int kk = 0; kk < 8; ++kk) v = fmaf(h8[kk], w[kk * 64], v);
#pragma unroll
    for (int off = 32; off > 0; off >>= 1) v += __shfl_xor(v, off, 64);
    nl[j] = 2.5f * tanhf((v + bn[j]) / 5.0f);
  }
  float ol[8];
#pragma unroll
  for (int j = 0; j < 8; ++j) {
    const float* w = wopi + (size_t)j * Hsz + lane;
    float v = 0.0f;
#pragma unroll
    for (int kk = 0; kk < 8; ++kk) v = fmaf(h8[kk], w[kk * 64], v);
#pragma unroll
    for (int off = 32; off > 0; off >>= 1) v += __shfl_xor(v, off, 64);
    ol[j] = (v + bopi[j]) / 5.0f;
  }

  {
    const float* g = gum + (size_t)r * 8;
    float m = nl[0];
#pragma unroll
    for (int j = 1; j < K; ++j) m = fmaxf(m, nl[j]);
    float se = 0.0f;
#pragma unroll
    for (int j = 0; j < K; ++j) se += expf(nl[j] - m);
    float lse = logf(se);
    int a = 0;
    float best = nl[0] + g[0];
#pragma unroll
    for (int j = 1; j < K; ++j) {
      float v = nl[j] + g[j];
      if (v > best) { best = v; a = j; }
    }
    float ent = 0.0f, sel = 0.0f;
#pragma unroll
    for (int j = 0; j < K; ++j) {
      float lp = nl[j] - m - lse;
      ent -= lp * expf(lp);
      if (j == a) sel = lp;
    }
    if (lane == 0) { oan[r] = (float)a; oln[r] = sel; oen[r] = ent; }
  }
  {
    const float* g = gum + (size_t)Bsz * 8 + (size_t)r * 8;
    float m = ol[0];
#pragma unroll
    for (int j = 1; j < 8; ++j) m = fmaxf(m, ol[j]);
    float se = 0.0f;
#pragma unroll
    for (int j = 0; j < 8; ++j) se += expf(ol[j] - m);
    float lse = logf(se);
    int a = 0;
    float best = ol[0] + g[0];
#pragma unroll
    for (int j = 1; j < 8; ++j) {
      float v = ol[j] + g[j];
      if (v > best) { best = v; a = j; }
    }
    float ent = 0.0f, sel = 0.0f;
#pragma unroll
    for (int j = 0; j < 8; ++j) {
      float lp = ol[j] - m - lse;
      ent -= lp * expf(lp);
      if (j == a) sel = lp;
    }
    if (lane == 0) {
      oao[r] = (float)a; olo[r] = sel; oeo[r] = ent;
      act_next[r] = a;
      if (cls_out) cls_out[r] = (cls_prev ? cls_prev[r] * 8 : 0) + a;
    }
  }
}

// ---------------- decide on global h (steps 1,2,3,5,6,7) -------------------
template <int K>
__global__ __launch_bounds__(256) void decide_step(
    const float* __restrict__ h, const float* __restrict__ wn,
    const float* __restrict__ bn, const float* __restrict__ wopi,
    const float* __restrict__ bopi, const float* __restrict__ gum,
    float* __restrict__ oan, float* __restrict__ oao,
    float* __restrict__ oln, float* __restrict__ olo,
    float* __restrict__ oen, float* __restrict__ oeo,
    int* __restrict__ act_next, const int* __restrict__ hidx, int hmode,
    const int* __restrict__ cls_prev, int* __restrict__ cls_out) {
  const int lane = threadIdx.x & 63;
  const int r = (blockIdx.x << 2) + (threadIdx.x >> 6);
  const int idx = (hmode == 1) ? r : hidx[r];
  const float* hr = h + (size_t)idx * Hsz;
  const float4 hv0 = *(const float4*)(hr + (lane << 3));
  const float4 hv1 = *(const float4*)(hr + (lane << 3) + 4);
  decide_core<K>(hv0, hv1, lane, r, wn, bn, wopi, bopi, gum, oan, oao, oln,
                 olo, oen, oeo, act_next, cls_prev, cls_out);
}

// ---------------- step 0: h1 recomputed per-lane from Eperm[0] + decide ----
__global__ __launch_bounds__(256) void decide0_step(
    const float* __restrict__ Eperm, const float* __restrict__ wn,
    const float* __restrict__ bn, const float* __restrict__ wopi,
    const float* __restrict__ bopi, const float* __restrict__ gum,
    float* __restrict__ oan, float* __restrict__ oao,
    float* __restrict__ oln, float* __restrict__ olo,
    float* __restrict__ oen, float* __restrict__ oeo,
    int* __restrict__ act_next, int* __restrict__ cls_out) {
  const int lane = threadIdx.x & 63;
  const int r = (blockIdx.x << 2) + (threadIdx.x >> 6);
  float h8[8];
#pragma unroll
  for (int kk = 0; kk < 8; ++kk) {
    float4 e = *(const float4*)&Eperm[(size_t)(((lane << 3) + kk) << 2)];
    float ig = sigf(e.x);
    float gg = tanhf(e.z);
    float og = sigf(e.w);
    float cn = ig * gg;  // c_prev = 0
    h8[kk] = og * tanhf(cn);
  }
  float4 hv0 = {h8[0], h8[1], h8[2], h8[3]};
  float4 hv1 = {h8[4], h8[5], h8[6], h8[7]};
  decide_core<2>(hv0, hv1, lane, r, wn, bn, wopi, bopi, gum, oan, oao, oln,
                 olo, oen, oeo, act_next, nullptr, cls_out);
}

// ---------------- step 1: wave per j, 4 gate dots on h1 + pw (8 classes) ---
__global__ __launch_bounds__(256) void fused_step1(
    const float* __restrict__ Eperm, const float* __restrict__ w_hh,
    float* __restrict__ h2, float* __restrict__ c2) {
  const int lane = threadIdx.x & 63;
  const int j = (blockIdx.x << 2) + (threadIdx.x >> 6);  // 0..511
  float h8[8];
#pragma unroll
  for (int kk = 0; kk < 8; ++kk) {
    float4 e = *(const float4*)&Eperm[(size_t)(((lane << 3) + kk) << 2)];
    h8[kk] = sigf(e.w) * tanhf(sigf(e.x) * tanhf(e.z));
  }
  float v[4];
#pragma unroll
  for (int g = 0; g < 4; ++g) {
    const float* w = w_hh + (size_t)(g * 512 + j) * Hsz + (lane << 3);
    float4 w0 = *(const float4*)(w);
    float4 w1 = *(const float4*)(w + 4);
    v[g] = h8[0] * w0.x + h8[1] * w0.y + h8[2] * w0.z + h8[3] * w0.w +
           h8[4] * w1.x + h8[5] * w1.y + h8[6] * w1.z + h8[7] * w1.w;
  }
#pragma unroll
  for (int off = 32; off > 0; off >>= 1) {
#pragma unroll
    for (int g = 0; g < 4; ++g) v[g] += __shfl_xor(v[g], off, 64);
  }
  float4 e0 = *(const float4*)&Eperm[(size_t)(j << 2)];
  float c1j = sigf(e0.x) * tanhf(e0.z);
  if (lane < 8) {
    const int er = lane;
    float4 e = *(const float4*)&Eperm[(size_t)er * G4H + (j << 2)];
    float ig = sigf(v[0] + e.x);
    float fg = sigf(v[1] + e.y);
    float gg = tanhf(v[2] + e.z);
    float og = sigf(v[3] + e.w);
    float cn = fg * c1j + ig * gg;
    h2[er * Hsz + j] = og * tanhf(cn);
    c2[er * Hsz + j] = cn;
  }
}

// ---------------- step 2: wave per (gq,j), dots on h2[gq] + pw -------------
__global__ __launch_bounds__(256) void fused_step2(
    const float* __restrict__ Eperm, const float* __restrict__ w_hh,
    const float* __restrict__ h2, const float* __restrict__ c2,
    float* __restrict__ h3, float* __restrict__ c3) {
  const int lane = threadIdx.x & 63;
  const int wid = (blockIdx.x << 2) + (threadIdx.x >> 6);  // 0..4095
  const int gq = wid >> 9, j = wid & 511;
  const float* hr = h2 + (size_t)gq * Hsz + (lane << 3);
  float4 a0 = *(const float4*)(hr);
  float4 a1 = *(const float4*)(hr + 4);
  float v[4];
#pragma unroll
  for (int g = 0; g < 4; ++g) {
    const float* w = w_hh + (size_t)(g * 512 + j) * Hsz + (lane << 3);
    float4 w0 = *(const float4*)(w);
    float4 w1 = *(const float4*)(w + 4);
    v[g] = a0.x * w0.x + a0.y * w0.y + a0.z * w0.z + a0.w * w0.w +
           a1.x * w1.x + a1.y * w1.y + a1.z * w1.z + a1.w * w1.w;
  }
#pragma unroll
  for (int off = 32; off > 0; off >>= 1) {
#pragma unroll
    for (int g = 0; g < 4; ++g) v[g] += __shfl_xor(v[g], off, 64);
  }
  float cp = c2[(size_t)gq * Hsz + j];
  if (lane < 8) {
    const int er = lane;
    float4 e = *(const float4*)&Eperm[(size_t)er * G4H + (j << 2)];
    float ig = sigf(v[0] + e.x);
    float fg = sigf(v[1] + e.y);
    float gg = tanhf(v[2] + e.z);
    float og = sigf(v[3] + e.w);
    float cn = fg * cp + ig * gg;
    h3[(size_t)((gq << 3) + er) * Hsz + j] = og * tanhf(cn);
    c3[(size_t)((gq << 3) + er) * Hsz + j] = cn;
  }
}

// ---------------- 64x64-tiled fp32 GEMM in ct-space (steps 3/4) ------------
template <int MODE>
__global__ __launch_bounds__(256) void gemm64ct(
    const float* __restrict__ A, const float* __restrict__ w_hh,
    const float* __restrict__ Eperm, const float* __restrict__ c_in,
    float* __restrict__ Gperm, float* __restrict__ h_o,
    float* __restrict__ c_o) {
  constexpr int LDA = 68;
  __shared__ float As[16 * LDA];
  __shared__ float Bs[16 * LDA];
  const int tid = threadIdx.x;
  const int bx = blockIdx.x & 31;
  const int by = blockIdx.x >> 5;
  const int r0 = by * 64, c0 = bx * 64;
  const int tx = tid & 15, ty = tid >> 4;
  const int lr = tid >> 2;
  const int lk = (tid & 3) << 2;
  const int ct = c0 + lr;
  const int brow = (ct & 3) * 512 + (ct >> 2);
  const float* Ar = A + (size_t)(r0 + lr) * Hsz;
  const float* Br = w_hh + (size_t)brow * Hsz;
  float acc[4][4];
#pragma unroll
  for (int i = 0; i < 4; ++i)
#pragma unroll
    for (int j = 0; j < 4; ++j) acc[i][j] = 0.0f;

  for (int k0 = 0; k0 < Hsz; k0 += 16) {
    float4 a = *(const float4*)(Ar + k0 + lk);
    float4 b = *(const float4*)(Br + k0 + lk);
    __syncthreads();
    As[(lk + 0) * LDA + lr] = a.x;
    As[(lk + 1) * LDA + lr] = a.y;
    As[(lk + 2) * LDA + lr] = a.z;
    As[(lk + 3) * LDA + lr] = a.w;
    Bs[(lk + 0) * LDA + lr] = b.x;
    Bs[(lk + 1) * LDA + lr] = b.y;
    Bs[(lk + 2) * LDA + lr] = b.z;
    Bs[(lk + 3) * LDA + lr] = b.w;
    __syncthreads();
#pragma unroll
    for (int kk = 0; kk < 16; ++kk) {
      float4 av = *(const float4*)&As[kk * LDA + (ty << 2)];
      float4 bv = *(const float4*)&Bs[kk * LDA + (tx << 2)];
      float avs[4] = {av.x, av.y, av.z, av.w};
      float bvs[4] = {bv.x, bv.y, bv.z, bv.w};
#pragma unroll
      for (int i = 0; i < 4; ++i)
#pragma unroll
        for (int j = 0; j < 4; ++j) acc[i][j] = fmaf(avs[i], bvs[j], acc[i][j]);
    }
  }
  const int jcol = (c0 >> 2) + tx;  // 0..511
  if (MODE == 0) {
#pragma unroll
    for (int i = 0; i < 4; ++i) {
      float4 o = {acc[i][0], acc[i][1], acc[i][2], acc[i][3]};
      *(float4*)&Gperm[(size_t)(r0 + (ty << 2) + i) * G4H + (jcol << 2)] = o;
    }
  } else {
#pragma unroll
    for (int i = 0; i < 4; ++i) {
      const int q = r0 + (ty << 2) + i;
      float cp = c_in[(size_t)q * Hsz + jcol];
#pragma unroll
      for (int er = 0; er < 8; ++er) {
        float4 e = *(const float4*)&Eperm[(size_t)er * G4H + (jcol << 2)];
        float ig = sigf(acc[i][0] + e.x);
        float fg = sigf(acc[i][1] + e.y);
        float gg = tanhf(acc[i][2] + e.z);
        float og = sigf(acc[i][3] + e.w);
        float cn = fg * cp + ig * gg;
        h_o[(size_t)((q << 3) + er) * Hsz + jcol] = og * tanhf(cn);
        c_o[(size_t)((q << 3) + er) * Hsz + jcol] = cn;
      }
    }
  }
}

// ---------------- step 4 expand + decide4 fused (wave/row, STRIDED) --------
__global__ __launch_bounds__(256) void decide4_fused(
    const float* __restrict__ Gperm, const float* __restrict__ Eperm,
    const float* __restrict__ c4, const int* __restrict__ cls,
    float* __restrict__ cF, ushort_t* __restrict__ Acat,
    const float* __restrict__ wn, const float* __restrict__ bn,
    const float* __restrict__ wopi, const float* __restrict__ bopi,
    const float* __restrict__ gum, float* __restrict__ oan,
    float* __restrict__ oao, float* __restrict__ oln, float* __restrict__ olo,
    float* __restrict__ oen, float* __restrict__ oeo,
    int* __restrict__ act) {
  const int lane = threadIdx.x & 63;
  const int r = (blockIdx.x << 2) + (threadIdx.x >> 6);
  const int q = cls[r];
  const int er = act[r];  // read BEFORE decide overwrites act[r]
  const float* Gr = Gperm + (size_t)q * G4H;
  const float* Er = Eperm + (size_t)er * G4H;
  float h8[8];
#pragma unroll
  for (int kk = 0; kk < 8; ++kk) {
    const int j = kk * 64 + lane;  // strided-lane: coalesced per instruction
    float4 g4 = *(const float4*)&Gr[j << 2];
    float4 e4 = *(const float4*)&Er[j << 2];
    float ig = sigf(g4.x + e4.x);
    float fg = sigf(g4.y + e4.y);
    float gg = tanhf(g4.z + e4.z);
    float og = sigf(g4.w + e4.w);
    float cn = fg * c4[(size_t)q * Hsz + j] + ig * gg;
    float hn = og * tanhf(cn);
    cF[(size_t)r * Hsz + j] = cn;
    h8[kk] = hn;
    ushort_t hi = f2bf_hi(hn);
    Acat[(size_t)r * 1024 + j] = hi;
    Acat[(size_t)r * 1024 + 512 + j] = f2bf_hi(hn - bf2f(hi));
  }
  decide_core_s<4>(h8, lane, r, wn, bn, wopi, bopi, gum, oan, oao, oln,
                   olo, oen, oeo, act, nullptr, nullptr);
}

// ---------------- split-bf16 MFMA GEMM + fused LSTM pointwise --------------
// C[4096 x 2048ct] = Ahi@Whi + Ahi@Wlo + Alo@Whi  (per K=32 super-iteration)
// tile 128x128, 4 waves x (4x4 16x16x32 tiles).
// R11 hybrid: B via glds16->LDS 2-slice prefetch (16KB/slice); A direct
// L2->VGPR double-buffered, loads issued before the barrier (its vmcnt(0)
// drain covers them; __syncthreads is a memory fence so they cannot sink).
__global__ __launch_bounds__(256, 2) void gemm_bf16_lstm(
    const ushort_t* __restrict__ Acat, const ushort_t* __restrict__ Wcat,
    const float* __restrict__ Eperm, const int* __restrict__ act,
    float* __restrict__ cF, float* __restrict__ h_out,
    ushort_t* __restrict__ Aout) {
  __shared__ union {
    ushort_t B[2][2][128 * 32];  // [slice][BH,BL][row*32+k] = 32 KB
    float C[64 * 132];           // 33.8 KB epilogue staging
  } sm;

  const int tid = threadIdx.x;
  const int wave = tid >> 6, lane = tid & 63;
  // XCD-aware superblock swizzle (bijective: 512 = 8 XCD x 64).
  const int xcd = blockIdx.x & 7;
  const int i64 = blockIdx.x >> 3;
  const int by = ((xcd >> 1) << 3) + (i64 >> 3);  // 32 row tiles
  const int bx = ((xcd & 1) << 3) + (i64 & 7);    // 16 col tiles
  const int r0 = by * 128, c0 = bx * 128;
  const int wr = (wave >> 1) * 64, wc = (wave & 1) * 64;
  const int mrow = lane & 15, quad = lane >> 4;

  // B staging: 16 wave-loads per 16KB slice (regions of 16 rows x 32 k);
  // 4 glds16 per thread.
  const int srow = lane >> 2;      // row-in-region 0..15
  const int sk = (lane & 3) << 3;  // k-elem offset 0,8,16,24
  const ushort_t* sbase[4];
  int doff[4];
#pragma unroll
  for (int q = 0; q < 4; ++q) {
    const int g = (q << 2) + wave;  // 0..15 unique
    const int half = g >> 3;        // 0=BH 1=BL
    const int region = g & 7;
    const int row = region * 16 + srow;
    sbase[q] = Wcat + (size_t)(c0 + row) * 1536 + half * 512 + sk;
    doff[q] = half * 8192 + region * 1024;  // bytes within slice
  }

  // A fragment base addresses (direct per-lane L2 loads).
  const ushort_t* aRow[4];
#pragma unroll
  for (int i = 0; i < 4; ++i)
    aRow[i] = Acat + (size_t)(r0 + wr + i * 16 + mrow) * 1024 + (quad << 3);

  f32x4 acc[4][4];
#pragma unroll
  for (int i = 0; i < 4; ++i)
#pragma unroll
    for (int jt = 0; jt < 4; ++jt) acc[i][jt] = (f32x4){0.f, 0.f, 0.f, 0.f};

  auto stageB = [&](int buf, int it) {
    const int ks = it << 5;
#pragma unroll
    for (int q = 0; q < 4; ++q)
      glds16(sbase[q] + ks, (char*)sm.B[buf][0] + doff[q]);
  };
  auto loadA = [&](short8* ah, short8* al, int it) {
    const int ks = it << 5;
#pragma unroll
    for (int i = 0; i < 4; ++i) {
      ah[i] = *(const short8*)(aRow[i] + ks);
      al[i] = *(const short8*)(aRow[i] + 512 + ks);
    }
  };
  auto compute = [&](const short8* ah, const short8* al, int buf) {
    short8 bh[4], bl[4];
#pragma unroll
    for (int jt = 0; jt < 4; ++jt) {
      const int off = (wc + jt * 16 + mrow) * 32 + (quad << 3);
      bh[jt] = *(const short8*)&sm.B[buf][0][off];
      bl[jt] = *(const short8*)&sm.B[buf][1][off];
    }
#pragma unroll
    for (int i = 0; i < 4; ++i)
#pragma unroll
      for (int jt = 0; jt < 4; ++jt) {
        acc[i][jt] = __builtin_amdgcn_mfma_f32_16x16x32_bf16(
            ah[i], bh[jt], acc[i][jt], 0, 0, 0);
        acc[i][jt] = __builtin_amdgcn_mfma_f32_16x16x32_bf16(
            ah[i], bl[jt], acc[i][jt], 0, 0, 0);
        acc[i][jt] = __builtin_amdgcn_mfma_f32_16x16x32_bf16(
            al[i], bh[jt], acc[i][jt], 0, 0, 0);
      }
  };

  // prologue: slice 0 (B) + A(0) in regs; barrier drains both.
  short8 ah0[4], al0[4], ah1[4], al1[4];
  loadA(ah0, al0, 0);
  stageB(0, 0);
  __syncthreads();

  // main loop: prefetch (A->regs, B->LDS) for it+1 BEFORE compute(it);
  // trailing __syncthreads drains the prefetch while other block computes.
  for (int it2 = 0; it2 < 8; ++it2) {
    const int it = it2 << 1;
    // even iteration: consume buf0/A0, prefetch buf1/A1 for it+1 (<=15)
    loadA(ah1, al1, it + 1);
    stageB(1, it + 1);
    compute(ah0, al0, 0);
    __syncthreads();
    // odd iteration: consume buf1/A1, prefetch buf0/A0 for it+2 (if any)
    if (it + 2 < 16) {
      loadA(ah0, al0, it + 2);
      stageB(0, it + 2);
    }
    compute(ah1, al1, 1);
    __syncthreads();
  }

  // ---- epilogue: two 64-row phases through LDS, fused LSTM pointwise ----
  const int jj = tid & 31;         // j-local 0..31
  const int rbase = tid >> 5;      // 0..7
#pragma unroll
  for (int p = 0; p < 2; ++p) {
    __syncthreads();  // phase 0: K-loop reads done; phase 1: prev consume done
    if ((wr >> 6) == p) {
#pragma unroll
      for (int i = 0; i < 4; ++i)
#pragma unroll
        for (int jt = 0; jt < 4; ++jt)
#pragma unroll
          for (int rg = 0; rg < 4; ++rg)
            sm.C[(i * 16 + quad * 4 + rg) * 132 + wc + jt * 16 + mrow] =
                acc[i][jt][rg];
    }
    __syncthreads();
#pragma unroll
    for (int rp = 0; rp < 8; ++rp) {
      const int rl = rbase * 8 + rp;           // 0..63
      const int grow = r0 + p * 64 + rl;
      float4 g4 = *(float4*)&sm.C[rl * 132 + jj * 4];
      const int a = act[grow];
      const int jglob = (c0 >> 2) + jj;        // 0..511
      float4 e4 = *(const float4*)&Eperm[(size_t)a * G4H + c0 + jj * 4];
      float iv = g4.x + e4.x, fv = g4.y + e4.y;
      float gv = g4.z + e4.z, ov = g4.w + e4.w;
      float ig = 1.0f / (1.0f + expf(-iv));
      float fg = 1.0f / (1.0f + expf(-fv));
      float gg = tanhf(gv);
      float og = 1.0f / (1.0f + expf(-ov));
      const size_t ci = (size_t)grow * Hsz + jglob;
      float cn = fg * cF[ci] + ig * gg;
      float hn = og * tanhf(cn);
      cF[ci] = cn;
      h_out[ci] = hn;
      ushort_t hi = f2bf_hi(hn);
      Aout[(size_t)grow * 1024 + jglob] = hi;
      Aout[(size_t)grow * 1024 + 512 + jglob] = f2bf_hi(hn - bf2f(hi));
    }
  }
}

// ---------------------------------------------------------------------------
extern "C" void kernel_launch(void* const* d_in, const int* in_sizes, int n_in,
                              void* d_out, int out_size, void* d_ws,
                              size_t ws_size, hipStream_t stream) {
  (void)in_sizes; (void)n_in; (void)out_size; (void)ws_size;
  const float* emb = (const float*)d_in[0];
  const float* w_ih = (const float*)d_in[1];
  const float* w_hh = (const float*)d_in[2];
  const float* b_ih = (const float*)d_in[3];
  const float* b_hh = (const float*)d_in[4];
  const float* wn[4] = {(const float*)d_in[5], (const float*)d_in[7],
                        (const float*)d_in[9], (const float*)d_in[11]};
  const float* bn[4] = {(const float*)d_in[6], (const float*)d_in[8],
                        (const float*)d_in[10], (const float*)d_in[12]};
  const float* wop = (const float*)d_in[13];
  const float* bop = (const float*)d_in[14];
  const float* gum = (const float*)d_in[15];

  float* ws = (float*)d_ws;
  float* Eperm = ws;             ws += 9 * G4H;
  float* h2 = ws;                ws += 8 * Hsz;
  float* c2 = ws;                ws += 8 * Hsz;
  float* h3 = ws;                ws += 64 * Hsz;
  float* c3 = ws;                ws += 64 * Hsz;
  float* h4 = ws;                ws += 512 * Hsz;
  float* c4 = ws;                ws += 512 * Hsz;
  float* Gperm = ws;             // 4 MB used by early path...
  ushort_t* AcatB = (ushort_t*)Gperm;   // ...region reused (8 MB) from step 5
  ws += (8u << 20) / 4;
  ushort_t* AcatA = (ushort_t*)ws;      ws += (8u << 20) / 4;
  ushort_t* Wcat = (ushort_t*)ws;       ws += (6u << 20) / 4;
  float* hA = ws;                ws += (size_t)Bsz * Hsz;
  float* cF = ws;                ws += (size_t)Bsz * Hsz;
  int* act = (int*)ws;
  int* cls = act + Bsz;

  float* out = (float*)d_out;
  const size_t SZ = (size_t)16 * Bsz;

  auto outp = [&](int s, float*& oan, float*& oao, float*& oln, float*& olo,
                  float*& oen, float*& oeo, const float*& gn) {
    oan = out + (size_t)(2 * s) * Bsz;
    oao = out + (size_t)(2 * s + 1) * Bsz;
    oln = out + SZ + (size_t)(2 * s) * Bsz;
    olo = out + SZ + (size_t)(2 * s + 1) * Bsz;
    oen = out + 2 * SZ + (size_t)(2 * s) * Bsz;
    oeo = out + 2 * SZ + (size_t)(2 * s + 1) * Bsz;
    gn = gum + (size_t)(2 * s) * Bsz * 8;
  };

  auto decide = [&](int s, const float* h, int hmode, const int* hidx,
                    const int* cls_prev, int* cls_out) {
    const int i = s >> 1;
    float *oan, *oao, *oln, *olo, *oen, *oeo;
    const float* gn;
    outp(s, oan, oao, oln, olo, oen, oeo, gn);
    const float* wopi = wop + (size_t)i * 8 * Hsz;
    const float* bopi = bop + (size_t)i * 8;
    switch (i) {
      case 0:
        decide_step<2><<<Bsz / 4, 256, 0, stream>>>(h, wn[0], bn[0], wopi, bopi,
            gn, oan, oao, oln, olo, oen, oeo, act, hidx, hmode, cls_prev, cls_out);
        break;
      case 1:
        decide_step<3><<<Bsz / 4, 256, 0, stream>>>(h, wn[1], bn[1], wopi, bopi,
            gn, oan, oao, oln, olo, oen, oeo, act, hidx, hmode, cls_prev, cls_out);
        break;
      case 2:
        decide_step<4><<<Bsz / 4, 256, 0, stream>>>(h, wn[2], bn[2], wopi, bopi,
            gn, oan, oao, oln, olo, oen, oeo, act, hidx, hmode, cls_prev, cls_out);
        break;
      default:
        decide_step<5><<<Bsz / 4, 256, 0, stream>>>(h, wn[3], bn[3], wopi, bopi,
            gn, oan, oao, oln, olo, oen, oeo, act, hidx, hmode, cls_prev, cls_out);
        break;
    }
  };

  // setup: Eperm + Wcat in one launch
  setup_fused<<<4608 + 8192, 256, 0, stream>>>(emb, w_ih, b_ih, b_hh, w_hh,
                                               Eperm, Wcat);

  // step 0: decide on recomputed h1 (fused)
  {
    float *oan, *oao, *oln, *olo, *oen, *oeo;
    const float* gn;
    outp(0, oan, oao, oln, olo, oen, oeo, gn);
    decide0_step<<<Bsz / 4, 256, 0, stream>>>(Eperm, wn[0], bn[0], wop, bop,
        gn, oan, oao, oln, olo, oen, oeo, act, cls);
  }

  // step 1: fused class GEMM + pointwise -> 8-class h2,c2
  fused_step1<<<128, 256, 0, stream>>>(Eperm, w_hh, h2, c2);
  decide(1, h2, 2, cls, cls, cls);

  // step 2: fused class GEMM + pointwise -> 64-class h3,c3
  fused_step2<<<1024, 256, 0, stream>>>(Eperm, w_hh, h2, c2, h3, c3);
  decide(2, h3, 2, cls, cls, cls);

  // step 3: ct-space tiled GEMM + fused pointwise -> 512-class h4,c4
  gemm64ct<1><<<32, 256, 0, stream>>>(h3, w_hh, Eperm, c3, nullptr, h4, c4);
  decide(3, h4, 2, cls, nullptr, nullptr);

  // step 4: ct-space tiled GEMM -> Gperm; expand+decide fused (strided)
  gemm64ct<0><<<256, 256, 0, stream>>>(h4, w_hh, nullptr, nullptr, Gperm,
                                       nullptr, nullptr);
  {
    float *oan, *oao, *oln, *olo, *oen, *oeo;
    const float* gn;
    outp(4, oan, oao, oln, olo, oen, oeo, gn);
    decide4_fused<<<Bsz / 4, 256, 0, stream>>>(Gperm, Eperm, c4, cls, cF,
        AcatA, wn[2], bn[2], wop + (size_t)2 * 8 * Hsz, bop + 2 * 8, gn,
        oan, oao, oln, olo, oen, oeo, act);
  }

  // steps 5-7: split-bf16 MFMA GEMM + fused pointwise (A-cat ping-pong)
  ushort_t* ain = AcatA;
  ushort_t* aout = AcatB;
  for (int s = 5; s < 8; ++s) {
    gemm_bf16_lstm<<<512, 256, 0, stream>>>(ain, Wcat, Eperm, act, cF, hA, aout);
    decide(s, hA, 1, nullptr, nullptr, nullptr);
    ushort_t* t = ain; ain = aout; aout = t;
  }
}

// Round 9
// 373.625 us; speedup vs baseline: 1.5624x; 1.5624x over previous
//
#include <hip/hip_runtime.h>

// ---------------------------------------------------------------------------
// NASNet controller: 8 sequential LSTM steps (B=4096, H=512) + 16 decisions.
//  - Steps 1-4 run on class representatives (1/8/64/512 rows).
//  - Steps 5-7: full GEMMs on the MFMA pipe via split-bf16 (hi+lo) emulation:
//    C = Ahi@Whi + Ahi@Wlo + Alo@Whi.
//  - R5: XCD superblock blockIdx swizzle (per-XCD set ~fits 4MB L2).
//  - R6: shared-operand products (3 MFMAs per fragment pair), 2-slice
//    glds16 prefetch (2-phase) — PROVEN anchor (~38-46us/dispatch, R4).
//  - R7: launch fusions (setup, step0, steps 1/2, ct-space gemm64).
//  - R8: strided-lane decide4 (per-instruction coalescing).
//  - R9/R10/R11 GEMM-schedule experiments all regressed -> gemm_bf16_lstm
//    is the R4 version verbatim; declared at its 2-phase ceiling.
//  - R13: gemm64ct occupancy fix. R8 counters: step-3 at grid 32 = 1.4%
//    occupancy, 88-102us latency-chain (clock-sensitive). Split-K: step-3
//    K/8 -> 256 blocks + fused reduce/pointwise kernel; step-4 K/2 -> 512
//    blocks, decide4 sums the two partial planes inline.
// ---------------------------------------------------------------------------

constexpr int Bsz = 4096;
constexpr int Hsz = 512;
constexpr int G4H = 2048;

typedef unsigned short ushort_t;
using short8 = __attribute__((ext_vector_type(8))) short;
using f32x4 = __attribute__((ext_vector_type(4))) float;

__device__ __forceinline__ ushort_t f2bf_hi(float f) {
  unsigned u = __float_as_uint(f);
  u += 0x7FFF + ((u >> 16) & 1);  // RNE
  return (ushort_t)(u >> 16);
}
__device__ __forceinline__ float bf2f(ushort_t h) {
  return __uint_as_float((unsigned)h << 16);
}
__device__ __forceinline__ float sigf(float x) {
  return 1.0f / (1.0f + expf(-x));
}

__device__ __forceinline__ void glds16(const void* gsrc, void* ldst) {
  __builtin_amdgcn_global_load_lds(
      (const __attribute__((address_space(1))) void*)gsrc,
      (__attribute__((address_space(3))) void*)ldst, 16, 0, 0);
}

// ---------------- setup: Eperm (wave-per-col) + Wcat, one launch -----------
__global__ __launch_bounds__(256) void setup_fused(
    const float* __restrict__ emb, const float* __restrict__ w_ih,
    const float* __restrict__ b_ih, const float* __restrict__ b_hh,
    const float* __restrict__ w_hh, float* __restrict__ Eperm,
    ushort_t* __restrict__ Wcat) {
  if (blockIdx.x < 4608) {
    const int lane = threadIdx.x & 63;
    const int wid = (blockIdx.x << 2) + (threadIdx.x >> 6);  // t*2048 + col
    const int t = wid >> 11;
    const int col = wid & 2047;
    const float* er = emb + (size_t)t * Hsz + (lane << 3);
    const float* wr = w_ih + (size_t)col * Hsz + (lane << 3);
    float4 e0 = *(const float4*)(er);
    float4 e1 = *(const float4*)(er + 4);
    float4 w0 = *(const float4*)(wr);
    float4 w1 = *(const float4*)(wr + 4);
    float v = e0.x * w0.x + e0.y * w0.y + e0.z * w0.z + e0.w * w0.w +
              e1.x * w1.x + e1.y * w1.y + e1.z * w1.z + e1.w * w1.w;
#pragma unroll
    for (int off = 32; off > 0; off >>= 1) v += __shfl_xor(v, off, 64);
    if (lane == 0) {
      float val = v + b_ih[col] + b_hh[col];
      Eperm[(size_t)t * G4H + ((col & 511) << 2) + (col >> 9)] = val;
    }
  } else {
    const int b = blockIdx.x - 4608;
    const int ct = b >> 2;
    const int k = ((b & 3) << 8) + threadIdx.x;  // 0..1023
    const int j = ct >> 2, g = ct & 3;
    const float* srcrow = w_hh + (size_t)(g * 512 + j) * Hsz;
    ushort_t out;
    if (k < 512) {
      out = f2bf_hi(srcrow[k]);
    } else {
      float x = srcrow[k - 512];
      ushort_t hi = f2bf_hi(x);
      out = f2bf_hi(x - bf2f(hi));
    }
    Wcat[(size_t)ct * 1536 + k] = out;
  }
}

// ---------------- decide core (wave per row, h as float4 pair) -------------
template <int K>
__device__ __forceinline__ void decide_core(
    const float4 hv0, const float4 hv1, const int lane, const int r,
    const float* __restrict__ wn, const float* __restrict__ bn,
    const float* __restrict__ wopi, const float* __restrict__ bopi,
    const float* __restrict__ gum, float* __restrict__ oan,
    float* __restrict__ oao, float* __restrict__ oln, float* __restrict__ olo,
    float* __restrict__ oen, float* __restrict__ oeo,
    int* __restrict__ act_next, const int* __restrict__ cls_prev,
    int* __restrict__ cls_out) {
  float nl[K];
#pragma unroll
  for (int j = 0; j < K; ++j) {
    const float* w = wn + (size_t)j * Hsz;
    float4 w0 = *(const float4*)(w + (lane << 3));
    float4 w1 = *(const float4*)(w + (lane << 3) + 4);
    float v = hv0.x * w0.x + hv0.y * w0.y + hv0.z * w0.z + hv0.w * w0.w +
              hv1.x * w1.x + hv1.y * w1.y + hv1.z * w1.z + hv1.w * w1.w;
#pragma unroll
    for (int off = 32; off > 0; off >>= 1) v += __shfl_xor(v, off, 64);
    nl[j] = 2.5f * tanhf((v + bn[j]) / 5.0f);
  }
  float ol[8];
#pragma unroll
  for (int j = 0; j < 8; ++j) {
    const float* w = wopi + (size_t)j * Hsz;
    float4 w0 = *(const float4*)(w + (lane << 3));
    float4 w1 = *(const float4*)(w + (lane << 3) + 4);
    float v = hv0.x * w0.x + hv0.y * w0.y + hv0.z * w0.z + hv0.w * w0.w +
              hv1.x * w1.x + hv1.y * w1.y + hv1.z * w1.z + hv1.w * w1.w;
#pragma unroll
    for (int off = 32; off > 0; off >>= 1) v += __shfl_xor(v, off, 64);
    ol[j] = (v + bopi[j]) / 5.0f;
  }

  {
    const float* g = gum + (size_t)r * 8;
    float m = nl[0];
#pragma unroll
    for (int j = 1; j < K; ++j) m = fmaxf(m, nl[j]);
    float se = 0.0f;
#pragma unroll
    for (int j = 0; j < K; ++j) se += expf(nl[j] - m);
    float lse = logf(se);
    int a = 0;
    float best = nl[0] + g[0];
#pragma unroll
    for (int j = 1; j < K; ++j) {
      float v = nl[j] + g[j];
      if (v > best) { best = v; a = j; }
    }
    float ent = 0.0f, sel = 0.0f;
#pragma unroll
    for (int j = 0; j < K; ++j) {
      float lp = nl[j] - m - lse;
      ent -= lp * expf(lp);
      if (j == a) sel = lp;
    }
    if (lane == 0) { oan[r] = (float)a; oln[r] = sel; oen[r] = ent; }
  }
  {
    const float* g = gum + (size_t)Bsz * 8 + (size_t)r * 8;
    float m = ol[0];
#pragma unroll
    for (int j = 1; j < 8; ++j) m = fmaxf(m, ol[j]);
    float se = 0.0f;
#pragma unroll
    for (int j = 0; j < 8; ++j) se += expf(ol[j] - m);
    float lse = logf(se);
    int a = 0;
    float best = ol[0] + g[0];
#pragma unroll
    for (int j = 1; j < 8; ++j) {
      float v = ol[j] + g[j];
      if (v > best) { best = v; a = j; }
    }
    float ent = 0.0f, sel = 0.0f;
#pragma unroll
    for (int j = 0; j < 8; ++j) {
      float lp = ol[j] - m - lse;
      ent -= lp * expf(lp);
      if (j == a) sel = lp;
    }
    if (lane == 0) {
      oao[r] = (float)a; olo[r] = sel; oeo[r] = ent;
      act_next[r] = a;
      if (cls_out) cls_out[r] = (cls_prev ? cls_prev[r] * 8 : 0) + a;
    }
  }
}

// ---------------- decide core, STRIDED h layout: lane holds h[kk*64+lane] --
template <int K>
__device__ __forceinline__ void decide_core_s(
    const float* __restrict__ h8, const int lane, const int r,
    const float* __restrict__ wn, const float* __restrict__ bn,
    const float* __restrict__ wopi, const float* __restrict__ bopi,
    const float* __restrict__ gum, float* __restrict__ oan,
    float* __restrict__ oao, float* __restrict__ oln, float* __restrict__ olo,
    float* __restrict__ oen, float* __restrict__ oeo,
    int* __restrict__ act_next, const int* __restrict__ cls_prev,
    int* __restrict__ cls_out) {
  float nl[K];
#pragma unroll
  for (int j = 0; j < K; ++j) {
    const float* w = wn + (size_t)j * Hsz + lane;
    float v = 0.0f;
#pragma unroll
    for (int kk = 0; kk < 8; ++kk) v = fmaf(h8[kk], w[kk * 64], v);
#pragma unroll
    for (int off = 32; off > 0; off >>= 1) v += __shfl_xor(v, off, 64);
    nl[j] = 2.5f * tanhf((v + bn[j]) / 5.0f);
  }
  float ol[8];
#pragma unroll
  for (int j = 0; j < 8; ++j) {
    const float* w = wopi + (size_t)j * Hsz + lane;
    float v = 0.0f;
#pragma unroll
    for (int kk = 0; kk < 8; ++kk) v = fmaf(h8[kk], w[kk * 64], v);
#pragma unroll
    for (int off = 32; off > 0; off >>= 1) v += __shfl_xor(v, off, 64);
    ol[j] = (v + bopi[j]) / 5.0f;
  }

  {
    const float* g = gum + (size_t)r * 8;
    float m = nl[0];
#pragma unroll
    for (int j = 1; j < K; ++j) m = fmaxf(m, nl[j]);
    float se = 0.0f;
#pragma unroll
    for (int j = 0; j < K; ++j) se += expf(nl[j] - m);
    float lse = logf(se);
    int a = 0;
    float best = nl[0] + g[0];
#pragma unroll
    for (int j = 1; j < K; ++j) {
      float v = nl[j] + g[j];
      if (v > best) { best = v; a = j; }
    }
    float ent = 0.0f, sel = 0.0f;
#pragma unroll
    for (int j = 0; j < K; ++j) {
      float lp = nl[j] - m - lse;
      ent -= lp * expf(lp);
      if (j == a) sel = lp;
    }
    if (lane == 0) { oan[r] = (float)a; oln[r] = sel; oen[r] = ent; }
  }
  {
    const float* g = gum + (size_t)Bsz * 8 + (size_t)r * 8;
    float m = ol[0];
#pragma unroll
    for (int j = 1; j < 8; ++j) m = fmaxf(m, ol[j]);
    float se = 0.0f;
#pragma unroll
    for (int j = 0; j < 8; ++j) se += expf(ol[j] - m);
    float lse = logf(se);
    int a = 0;
    float best = ol[0] + g[0];
#pragma unroll
    for (int j = 1; j < 8; ++j) {
      float v = ol[j] + g[j];
      if (v > best) { best = v; a = j; }
    }
    float ent = 0.0f, sel = 0.0f;
#pragma unroll
    for (int j = 0; j < 8; ++j) {
      float lp = ol[j] - m - lse;
      ent -= lp * expf(lp);
      if (j == a) sel = lp;
    }
    if (lane == 0) {
      oao[r] = (float)a; olo[r] = sel; oeo[r] = ent;
      act_next[r] = a;
      if (cls_out) cls_out[r] = (cls_prev ? cls_prev[r] * 8 : 0) + a;
    }
  }
}

// ---------------- decide on global h (steps 1,2,3,5,6,7) -------------------
template <int K>
__global__ __launch_bounds__(256) void decide_step(
    const float* __restrict__ h, const float* __restrict__ wn,
    const float* __restrict__ bn, const float* __restrict__ wopi,
    const float* __restrict__ bopi, const float* __restrict__ gum,
    float* __restrict__ oan, float* __restrict__ oao,
    float* __restrict__ oln, float* __restrict__ olo,
    float* __restrict__ oen, float* __restrict__ oeo,
    int* __restrict__ act_next, const int* __restrict__ hidx, int hmode,
    const int* __restrict__ cls_prev, int* __restrict__ cls_out) {
  const int lane = threadIdx.x & 63;
  const int r = (blockIdx.x << 2) + (threadIdx.x >> 6);
  const int idx = (hmode == 1) ? r : hidx[r];
  const float* hr = h + (size_t)idx * Hsz;
  const float4 hv0 = *(const float4*)(hr + (lane << 3));
  const float4 hv1 = *(const float4*)(hr + (lane << 3) + 4);
  decide_core<K>(hv0, hv1, lane, r, wn, bn, wopi, bopi, gum, oan, oao, oln,
                 olo, oen, oeo, act_next, cls_prev, cls_out);
}

// ---------------- step 0: h1 recomputed per-lane from Eperm[0] + decide ----
__global__ __launch_bounds__(256) void decide0_step(
    const float* __restrict__ Eperm, const float* __restrict__ wn,
    const float* __restrict__ bn, const float* __restrict__ wopi,
    const float* __restrict__ bopi, const float* __restrict__ gum,
    float* __restrict__ oan, float* __restrict__ oao,
    float* __restrict__ oln, float* __restrict__ olo,
    float* __restrict__ oen, float* __restrict__ oeo,
    int* __restrict__ act_next, int* __restrict__ cls_out) {
  const int lane = threadIdx.x & 63;
  const int r = (blockIdx.x << 2) + (threadIdx.x >> 6);
  float h8[8];
#pragma unroll
  for (int kk = 0; kk < 8; ++kk) {
    float4 e = *(const float4*)&Eperm[(size_t)(((lane << 3) + kk) << 2)];
    float ig = sigf(e.x);
    float gg = tanhf(e.z);
    float og = sigf(e.w);
    float cn = ig * gg;  // c_prev = 0
    h8[kk] = og * tanhf(cn);
  }
  float4 hv0 = {h8[0], h8[1], h8[2], h8[3]};
  float4 hv1 = {h8[4], h8[5], h8[6], h8[7]};
  decide_core<2>(hv0, hv1, lane, r, wn, bn, wopi, bopi, gum, oan, oao, oln,
                 olo, oen, oeo, act_next, nullptr, cls_out);
}

// ---------------- step 1: wave per j, 4 gate dots on h1 + pw (8 classes) ---
__global__ __launch_bounds__(256) void fused_step1(
    const float* __restrict__ Eperm, const float* __restrict__ w_hh,
    float* __restrict__ h2, float* __restrict__ c2) {
  const int lane = threadIdx.x & 63;
  const int j = (blockIdx.x << 2) + (threadIdx.x >> 6);  // 0..511
  float h8[8];
#pragma unroll
  for (int kk = 0; kk < 8; ++kk) {
    float4 e = *(const float4*)&Eperm[(size_t)(((lane << 3) + kk) << 2)];
    h8[kk] = sigf(e.w) * tanhf(sigf(e.x) * tanhf(e.z));
  }
  float v[4];
#pragma unroll
  for (int g = 0; g < 4; ++g) {
    const float* w = w_hh + (size_t)(g * 512 + j) * Hsz + (lane << 3);
    float4 w0 = *(const float4*)(w);
    float4 w1 = *(const float4*)(w + 4);
    v[g] = h8[0] * w0.x + h8[1] * w0.y + h8[2] * w0.z + h8[3] * w0.w +
           h8[4] * w1.x + h8[5] * w1.y + h8[6] * w1.z + h8[7] * w1.w;
  }
#pragma unroll
  for (int off = 32; off > 0; off >>= 1) {
#pragma unroll
    for (int g = 0; g < 4; ++g) v[g] += __shfl_xor(v[g], off, 64);
  }
  float4 e0 = *(const float4*)&Eperm[(size_t)(j << 2)];
  float c1j = sigf(e0.x) * tanhf(e0.z);
  if (lane < 8) {
    const int er = lane;
    float4 e = *(const float4*)&Eperm[(size_t)er * G4H + (j << 2)];
    float ig = sigf(v[0] + e.x);
    float fg = sigf(v[1] + e.y);
    float gg = tanhf(v[2] + e.z);
    float og = sigf(v[3] + e.w);
    float cn = fg * c1j + ig * gg;
    h2[er * Hsz + j] = og * tanhf(cn);
    c2[er * Hsz + j] = cn;
  }
}

// ---------------- step 2: wave per (gq,j), dots on h2[gq] + pw -------------
__global__ __launch_bounds__(256) void fused_step2(
    const float* __restrict__ Eperm, const float* __restrict__ w_hh,
    const float* __restrict__ h2, const float* __restrict__ c2,
    float* __restrict__ h3, float* __restrict__ c3) {
  const int lane = threadIdx.x & 63;
  const int wid = (blockIdx.x << 2) + (threadIdx.x >> 6);  // 0..4095
  const int gq = wid >> 9, j = wid & 511;
  const float* hr = h2 + (size_t)gq * Hsz + (lane << 3);
  float4 a0 = *(const float4*)(hr);
  float4 a1 = *(const float4*)(hr + 4);
  float v[4];
#pragma unroll
  for (int g = 0; g < 4; ++g) {
    const float* w = w_hh + (size_t)(g * 512 + j) * Hsz + (lane << 3);
    float4 w0 = *(const float4*)(w);
    float4 w1 = *(const float4*)(w + 4);
    v[g] = a0.x * w0.x + a0.y * w0.y + a0.z * w0.z + a0.w * w0.w +
           a1.x * w1.x + a1.y * w1.y + a1.z * w1.z + a1.w * w1.w;
  }
#pragma unroll
  for (int off = 32; off > 0; off >>= 1) {
#pragma unroll
    for (int g = 0; g < 4; ++g) v[g] += __shfl_xor(v[g], off, 64);
  }
  float cp = c2[(size_t)gq * Hsz + j];
  if (lane < 8) {
    const int er = lane;
    float4 e = *(const float4*)&Eperm[(size_t)er * G4H + (j << 2)];
    float ig = sigf(v[0] + e.x);
    float fg = sigf(v[1] + e.y);
    float gg = tanhf(v[2] + e.z);
    float og = sigf(v[3] + e.w);
    float cn = fg * cp + ig * gg;
    h3[(size_t)((gq << 3) + er) * Hsz + j] = og * tanhf(cn);
    c3[(size_t)((gq << 3) + er) * Hsz + j] = cn;
  }
}

// ---------------- split-K 64x64-tiled fp32 GEMM in ct-space ----------------
// NRT = row tiles (M/64), SK = K splits. Writes partials:
// Gpart[(s*NRT*64 + row)*G4H + ct-permuted col]. Grid = 32*NRT*SK.
template <int NRT, int SK>
__global__ __launch_bounds__(256) void gemm64ct_sk(
    const float* __restrict__ A, const float* __restrict__ w_hh,
    float* __restrict__ Gpart) {
  constexpr int LOG = (NRT == 1) ? 0 : (NRT == 2) ? 1 : (NRT == 4) ? 2 : 3;
  constexpr int LDA = 68;
  __shared__ float As[16 * LDA];
  __shared__ float Bs[16 * LDA];
  const int tid = threadIdx.x;
  const int bx = blockIdx.x & 31;
  const int by = (blockIdx.x >> 5) & (NRT - 1);
  const int s = blockIdx.x >> (5 + LOG);
  const int r0 = by * 64, c0 = bx * 64;
  const int tx = tid & 15, ty = tid >> 4;
  const int lr = tid >> 2;
  const int lk = (tid & 3) << 2;
  const int ct = c0 + lr;
  const int brow = (ct & 3) * 512 + (ct >> 2);
  const float* Ar = A + (size_t)(r0 + lr) * Hsz;
  const float* Br = w_hh + (size_t)brow * Hsz;
  float acc[4][4];
#pragma unroll
  for (int i = 0; i < 4; ++i)
#pragma unroll
    for (int j = 0; j < 4; ++j) acc[i][j] = 0.0f;

  const int kBeg = s * (Hsz / SK);
  const int kEnd = kBeg + Hsz / SK;
  for (int k0 = kBeg; k0 < kEnd; k0 += 16) {
    float4 a = *(const float4*)(Ar + k0 + lk);
    float4 b = *(const float4*)(Br + k0 + lk);
    __syncthreads();
    As[(lk + 0) * LDA + lr] = a.x;
    As[(lk + 1) * LDA + lr] = a.y;
    As[(lk + 2) * LDA + lr] = a.z;
    As[(lk + 3) * LDA + lr] = a.w;
    Bs[(lk + 0) * LDA + lr] = b.x;
    Bs[(lk + 1) * LDA + lr] = b.y;
    Bs[(lk + 2) * LDA + lr] = b.z;
    Bs[(lk + 3) * LDA + lr] = b.w;
    __syncthreads();
#pragma unroll
    for (int kk = 0; kk < 16; ++kk) {
      float4 av = *(const float4*)&As[kk * LDA + (ty << 2)];
      float4 bv = *(const float4*)&Bs[kk * LDA + (tx << 2)];
      float avs[4] = {av.x, av.y, av.z, av.w};
      float bvs[4] = {bv.x, bv.y, bv.z, bv.w};
#pragma unroll
      for (int i = 0; i < 4; ++i)
#pragma unroll
        for (int j = 0; j < 4; ++j) acc[i][j] = fmaf(avs[i], bvs[j], acc[i][j]);
    }
  }
  const int jcol = (c0 >> 2) + tx;  // 0..511
#pragma unroll
  for (int i = 0; i < 4; ++i) {
    float4 o = {acc[i][0], acc[i][1], acc[i][2], acc[i][3]};
    *(float4*)&Gpart[((size_t)(s * NRT * 64) + r0 + (ty << 2) + i) * G4H +
                     (jcol << 2)] = o;
  }
}

// ---------------- step 3: reduce 8 partials + LSTM pointwise ---------------
__global__ __launch_bounds__(256) void fused_step3red(
    const float* __restrict__ Gpart, const float* __restrict__ Eperm,
    const float* __restrict__ c3, float* __restrict__ h4,
    float* __restrict__ c4) {
  const int idx = blockIdx.x * 256 + threadIdx.x;  // 0..32767
  const int q = idx >> 9, j = idx & 511;
  float4 g = {0.f, 0.f, 0.f, 0.f};
#pragma unroll
  for (int s = 0; s < 8; ++s) {
    float4 p = *(const float4*)&Gpart[(size_t)(s * 64 + q) * G4H + (j << 2)];
    g.x += p.x; g.y += p.y; g.z += p.z; g.w += p.w;
  }
  const float cp = c3[(size_t)q * Hsz + j];
#pragma unroll
  for (int er = 0; er < 8; ++er) {
    float4 e = *(const float4*)&Eperm[(size_t)er * G4H + (j << 2)];
    float ig = sigf(g.x + e.x);
    float fg = sigf(g.y + e.y);
    float gg = tanhf(g.z + e.z);
    float og = sigf(g.w + e.w);
    float cn = fg * cp + ig * gg;
    h4[(size_t)((q << 3) + er) * Hsz + j] = og * tanhf(cn);
    c4[(size_t)((q << 3) + er) * Hsz + j] = cn;
  }
}

// ---------------- step 4 expand + decide4 fused (wave/row, STRIDED) --------
// Sums the two split-K partial planes inline.
__global__ __launch_bounds__(256) void decide4_fused(
    const float* __restrict__ Gperm, const float* __restrict__ Gperm2,
    const float* __restrict__ Eperm, const float* __restrict__ c4,
    const int* __restrict__ cls, float* __restrict__ cF,
    ushort_t* __restrict__ Acat, const float* __restrict__ wn,
    const float* __restrict__ bn, const float* __restrict__ wopi,
    const float* __restrict__ bopi, const float* __restrict__ gum,
    float* __restrict__ oan, float* __restrict__ oao,
    float* __restrict__ oln, float* __restrict__ olo,
    float* __restrict__ oen, float* __restrict__ oeo,
    int* __restrict__ act) {
  const int lane = threadIdx.x & 63;
  const int r = (blockIdx.x << 2) + (threadIdx.x >> 6);
  const int q = cls[r];
  const int er = act[r];  // read BEFORE decide overwrites act[r]
  const float* Gr = Gperm + (size_t)q * G4H;
  const float* Gr2 = Gperm2 + (size_t)q * G4H;
  const float* Er = Eperm + (size_t)er * G4H;
  float h8[8];
#pragma unroll
  for (int kk = 0; kk < 8; ++kk) {
    const int j = kk * 64 + lane;  // strided-lane: coalesced per instruction
    float4 g4 = *(const float4*)&Gr[j << 2];
    float4 p4 = *(const float4*)&Gr2[j << 2];
    float4 e4 = *(const float4*)&Er[j << 2];
    float ig = sigf(g4.x + p4.x + e4.x);
    float fg = sigf(g4.y + p4.y + e4.y);
    float gg = tanhf(g4.z + p4.z + e4.z);
    float og = sigf(g4.w + p4.w + e4.w);
    float cn = fg * c4[(size_t)q * Hsz + j] + ig * gg;
    float hn = og * tanhf(cn);
    cF[(size_t)r * Hsz + j] = cn;
    h8[kk] = hn;
    ushort_t hi = f2bf_hi(hn);
    Acat[(size_t)r * 1024 + j] = hi;
    Acat[(size_t)r * 1024 + 512 + j] = f2bf_hi(hn - bf2f(hi));
  }
  decide_core_s<4>(h8, lane, r, wn, bn, wopi, bopi, gum, oan, oao, oln,
                   olo, oen, oeo, act, nullptr, nullptr);
}

// ---------------- split-bf16 MFMA GEMM + fused LSTM pointwise --------------
// C[4096 x 2048ct] = Ahi@Whi + Ahi@Wlo + Alo@Whi  (per K=32 super-iteration)
// tile 128x128, 4 waves x (4x4 16x16x32 tiles). Panels: [128 rows][32 K] bf16.
// R4-PROVEN version: 2-slice glds16 prefetch, 2 barriers/iter.
__global__ __launch_bounds__(256) void gemm_bf16_lstm(
    const ushort_t* __restrict__ Acat, const ushort_t* __restrict__ Wcat,
    const float* __restrict__ Eperm, const int* __restrict__ act,
    float* __restrict__ cF, float* __restrict__ h_out,
    ushort_t* __restrict__ Aout) {
  __shared__ union {
    ushort_t P[2][4][128 * 32];  // [buf][AH,AL,BH,BL][row*32+k] = 64 KB
    float C[64 * 132];           // 33.8 KB epilogue staging
  } sm;

  const int tid = threadIdx.x;
  const int wave = tid >> 6, lane = tid & 63;
  // XCD-aware superblock swizzle (bijective: 512 = 8 XCD x 64).
  const int xcd = blockIdx.x & 7;
  const int i64 = blockIdx.x >> 3;
  const int by = ((xcd >> 1) << 3) + (i64 >> 3);  // 32 row tiles
  const int bx = ((xcd & 1) << 3) + (i64 & 7);    // 16 col tiles
  const int r0 = by * 128, c0 = bx * 128;
  const int wr = (wave >> 1) * 64, wc = (wave & 1) * 64;
  const int mrow = lane & 15, quad = lane >> 4;

  const int srow = lane >> 2;      // 0..15 within region
  const int sk = (lane & 3) << 3;  // k-element offset 0,8,16,24

  const ushort_t* sbase[8];
  int doff[8];
#pragma unroll
  for (int q = 0; q < 8; ++q) {
    const int g = (q << 2) + wave;   // 0..31 unique
    const int panel = g >> 3;        // 0=AH 1=AL 2=BH 3=BL
    const int region = g & 7;
    const int row = region * 16 + srow;
    if (panel == 0)
      sbase[q] = Acat + (size_t)(r0 + row) * 1024 + sk;
    else if (panel == 1)
      sbase[q] = Acat + (size_t)(r0 + row) * 1024 + 512 + sk;
    else if (panel == 2)
      sbase[q] = Wcat + (size_t)(c0 + row) * 1536 + sk;
    else
      sbase[q] = Wcat + (size_t)(c0 + row) * 1536 + 512 + sk;
    doff[q] = panel * 8192 + region * 1024;  // byte offset within buffer
  }

  f32x4 acc[4][4];
#pragma unroll
  for (int i = 0; i < 4; ++i)
#pragma unroll
    for (int jt = 0; jt < 4; ++jt) acc[i][jt] = (f32x4){0.f, 0.f, 0.f, 0.f};

  auto stage = [&](int buf, int it) {
    const int ks = it << 5;  // K-element offset
#pragma unroll
    for (int q = 0; q < 8; ++q)
      glds16(sbase[q] + ks, (char*)sm.P[0][0] + (buf << 15) + doff[q]);
  };

  stage(0, 0);
  __syncthreads();

  int cur = 0;
  for (int it = 0; it < 16; ++it) {
    if (it < 15) stage(cur ^ 1, it + 1);  // prefetch next K-slice
    const ushort_t* AH = sm.P[cur][0];
    const ushort_t* AL = sm.P[cur][1];
    const ushort_t* BH = sm.P[cur][2];
    const ushort_t* BL = sm.P[cur][3];
    short8 ah[4], al[4], bh[4], bl[4];
#pragma unroll
    for (int i = 0; i < 4; ++i) {
      ah[i] = *(const short8*)&AH[(wr + i * 16 + mrow) * 32 + (quad << 3)];
      al[i] = *(const short8*)&AL[(wr + i * 16 + mrow) * 32 + (quad << 3)];
    }
#pragma unroll
    for (int jt = 0; jt < 4; ++jt) {
      bh[jt] = *(const short8*)&BH[(wc + jt * 16 + mrow) * 32 + (quad << 3)];
      bl[jt] = *(const short8*)&BL[(wc + jt * 16 + mrow) * 32 + (quad << 3)];
    }
#pragma unroll
    for (int i = 0; i < 4; ++i)
#pragma unroll
      for (int jt = 0; jt < 4; ++jt) {
        acc[i][jt] = __builtin_amdgcn_mfma_f32_16x16x32_bf16(
            ah[i], bh[jt], acc[i][jt], 0, 0, 0);
        acc[i][jt] = __builtin_amdgcn_mfma_f32_16x16x32_bf16(
            ah[i], bl[jt], acc[i][jt], 0, 0, 0);
        acc[i][jt] = __builtin_amdgcn_mfma_f32_16x16x32_bf16(
            al[i], bh[jt], acc[i][jt], 0, 0, 0);
      }
    __syncthreads();  // drains prefetch + protects buffer reuse
    cur ^= 1;
  }

  // ---- epilogue: two 64-row phases through LDS, fused LSTM pointwise ----
  const int jj = tid & 31;         // j-local 0..31
  const int rbase = tid >> 5;      // 0..7
#pragma unroll
  for (int p = 0; p < 2; ++p) {
    __syncthreads();  // phase 0: K-loop reads done; phase 1: prev consume done
    if ((wr >> 6) == p) {
#pragma unroll
      for (int i = 0; i < 4; ++i)
#pragma unroll
        for (int jt = 0; jt < 4; ++jt)
#pragma unroll
          for (int rg = 0; rg < 4; ++rg)
            sm.C[(i * 16 + quad * 4 + rg) * 132 + wc + jt * 16 + mrow] =
                acc[i][jt][rg];
    }
    __syncthreads();
#pragma unroll
    for (int rp = 0; rp < 8; ++rp) {
      const int rl = rbase * 8 + rp;           // 0..63
      const int grow = r0 + p * 64 + rl;
      float4 g4 = *(float4*)&sm.C[rl * 132 + jj * 4];
      const int a = act[grow];
      const int jglob = (c0 >> 2) + jj;        // 0..511
      float4 e4 = *(const float4*)&Eperm[(size_t)a * G4H + c0 + jj * 4];
      float iv = g4.x + e4.x, fv = g4.y + e4.y;
      float gv = g4.z + e4.z, ov = g4.w + e4.w;
      float ig = 1.0f / (1.0f + expf(-iv));
      float fg = 1.0f / (1.0f + expf(-fv));
      float gg = tanhf(gv);
      float og = 1.0f / (1.0f + expf(-ov));
      const size_t ci = (size_t)grow * Hsz + jglob;
      float cn = fg * cF[ci] + ig * gg;
      float hn = og * tanhf(cn);
      cF[ci] = cn;
      h_out[ci] = hn;
      ushort_t hi = f2bf_hi(hn);
      Aout[(size_t)grow * 1024 + jglob] = hi;
      Aout[(size_t)grow * 1024 + 512 + jglob] = f2bf_hi(hn - bf2f(hi));
    }
  }
}

// ---------------------------------------------------------------------------
extern "C" void kernel_launch(void* const* d_in, const int* in_sizes, int n_in,
                              void* d_out, int out_size, void* d_ws,
                              size_t ws_size, hipStream_t stream) {
  (void)in_sizes; (void)n_in; (void)out_size; (void)ws_size;
  const float* emb = (const float*)d_in[0];
  const float* w_ih = (const float*)d_in[1];
  const float* w_hh = (const float*)d_in[2];
  const float* b_ih = (const float*)d_in[3];
  const float* b_hh = (const float*)d_in[4];
  const float* wn[4] = {(const float*)d_in[5], (const float*)d_in[7],
                        (const float*)d_in[9], (const float*)d_in[11]};
  const float* bn[4] = {(const float*)d_in[6], (const float*)d_in[8],
                        (const float*)d_in[10], (const float*)d_in[12]};
  const float* wop = (const float*)d_in[13];
  const float* bop = (const float*)d_in[14];
  const float* gum = (const float*)d_in[15];

  float* ws = (float*)d_ws;
  float* Eperm = ws;             ws += 9 * G4H;
  float* h2 = ws;                ws += 8 * Hsz;
  float* c2 = ws;                ws += 8 * Hsz;
  float* h3 = ws;                ws += 64 * Hsz;
  float* c3 = ws;                ws += 64 * Hsz;
  float* h4 = ws;                ws += 512 * Hsz;
  float* c4 = ws;                ws += 512 * Hsz;
  float* Gperm = ws;             // 8 MB: split-K partials (steps 3,4)...
  ushort_t* AcatB = (ushort_t*)Gperm;   // ...region reused from step 5
  ws += (8u << 20) / 4;
  ushort_t* AcatA = (ushort_t*)ws;      ws += (8u << 20) / 4;
  ushort_t* Wcat = (ushort_t*)ws;       ws += (6u << 20) / 4;
  float* hA = ws;                ws += (size_t)Bsz * Hsz;
  float* cF = ws;                ws += (size_t)Bsz * Hsz;
  int* act = (int*)ws;
  int* cls = act + Bsz;

  float* out = (float*)d_out;
  const size_t SZ = (size_t)16 * Bsz;

  auto outp = [&](int s, float*& oan, float*& oao, float*& oln, float*& olo,
                  float*& oen, float*& oeo, const float*& gn) {
    oan = out + (size_t)(2 * s) * Bsz;
    oao = out + (size_t)(2 * s + 1) * Bsz;
    oln = out + SZ + (size_t)(2 * s) * Bsz;
    olo = out + SZ + (size_t)(2 * s + 1) * Bsz;
    oen = out + 2 * SZ + (size_t)(2 * s) * Bsz;
    oeo = out + 2 * SZ + (size_t)(2 * s + 1) * Bsz;
    gn = gum + (size_t)(2 * s) * Bsz * 8;
  };

  auto decide = [&](int s, const float* h, int hmode, const int* hidx,
                    const int* cls_prev, int* cls_out) {
    const int i = s >> 1;
    float *oan, *oao, *oln, *olo, *oen, *oeo;
    const float* gn;
    outp(s, oan, oao, oln, olo, oen, oeo, gn);
    const float* wopi = wop + (size_t)i * 8 * Hsz;
    const float* bopi = bop + (size_t)i * 8;
    switch (i) {
      case 0:
        decide_step<2><<<Bsz / 4, 256, 0, stream>>>(h, wn[0], bn[0], wopi, bopi,
            gn, oan, oao, oln, olo, oen, oeo, act, hidx, hmode, cls_prev, cls_out);
        break;
      case 1:
        decide_step<3><<<Bsz / 4, 256, 0, stream>>>(h, wn[1], bn[1], wopi, bopi,
            gn, oan, oao, oln, olo, oen, oeo, act, hidx, hmode, cls_prev, cls_out);
        break;
      case 2:
        decide_step<4><<<Bsz / 4, 256, 0, stream>>>(h, wn[2], bn[2], wopi, bopi,
            gn, oan, oao, oln, olo, oen, oeo, act, hidx, hmode, cls_prev, cls_out);
        break;
      default:
        decide_step<5><<<Bsz / 4, 256, 0, stream>>>(h, wn[3], bn[3], wopi, bopi,
            gn, oan, oao, oln, olo, oen, oeo, act, hidx, hmode, cls_prev, cls_out);
        break;
    }
  };

  // setup: Eperm + Wcat in one launch
  setup_fused<<<4608 + 8192, 256, 0, stream>>>(emb, w_ih, b_ih, b_hh, w_hh,
                                               Eperm, Wcat);

  // step 0: decide on recomputed h1 (fused)
  {
    float *oan, *oao, *oln, *olo, *oen, *oeo;
    const float* gn;
    outp(0, oan, oao, oln, olo, oen, oeo, gn);
    decide0_step<<<Bsz / 4, 256, 0, stream>>>(Eperm, wn[0], bn[0], wop, bop,
        gn, oan, oao, oln, olo, oen, oeo, act, cls);
  }

  // step 1: fused class GEMM + pointwise -> 8-class h2,c2
  fused_step1<<<128, 256, 0, stream>>>(Eperm, w_hh, h2, c2);
  decide(1, h2, 2, cls, cls, cls);

  // step 2: fused class GEMM + pointwise -> 64-class h3,c3
  fused_step2<<<1024, 256, 0, stream>>>(Eperm, w_hh, h2, c2, h3, c3);
  decide(2, h3, 2, cls, cls, cls);

  // step 3: split-K=8 ct-space GEMM (256 blocks) + fused reduce/pointwise
  gemm64ct_sk<1, 8><<<32 * 8, 256, 0, stream>>>(h3, w_hh, Gperm);
  fused_step3red<<<128, 256, 0, stream>>>(Gperm, Eperm, c3, h4, c4);
  decide(3, h4, 2, cls, nullptr, nullptr);

  // step 4: split-K=2 ct-space GEMM (512 blocks) -> two 4MB partial planes;
  // decide4 sums them inline.
  gemm64ct_sk<8, 2><<<32 * 8 * 2, 256, 0, stream>>>(h4, w_hh, Gperm);
  {
    float *oan, *oao, *oln, *olo, *oen, *oeo;
    const float* gn;
    outp(4, oan, oao, oln, olo, oen, oeo, gn);
    decide4_fused<<<Bsz / 4, 256, 0, stream>>>(Gperm,
        Gperm + (size_t)512 * G4H, Eperm, c4, cls, cF, AcatA, wn[2], bn[2],
        wop + (size_t)2 * 8 * Hsz, bop + 2 * 8, gn,
        oan, oao, oln, olo, oen, oeo, act);
  }

  // steps 5-7: split-bf16 MFMA GEMM + fused pointwise (A-cat ping-pong)
  ushort_t* ain = AcatA;
  ushort_t* aout = AcatB;
  for (int s = 5; s < 8; ++s) {
    gemm_bf16_lstm<<<512, 256, 0, stream>>>(ain, Wcat, Eperm, act, cF, hA, aout);
    decide(s, hA, 1, nullptr, nullptr, nullptr);
    ushort_t* t = ain; ain = aout; aout = t;
  }
}